// Round 8
// baseline (184.788 us; speedup 1.0000x reference)
//
#include <hip/hip_runtime.h>
#include <stdint.h>

// Problem constants
#define Bv  2
#define Tv  2048
#define Cv  1024
#define Hv  16
#define HDv 64
#define LOG2E 1.44269504088896340736f

typedef __bf16 bf16x8 __attribute__((ext_vector_type(8)));
typedef float f32x4 __attribute__((ext_vector_type(4)));
typedef unsigned short us4v __attribute__((ext_vector_type(4)));

#define VMCNT(n) asm volatile("s_waitcnt vmcnt(" #n ")" ::: "memory")
#define LGKM0()  asm volatile("s_waitcnt lgkmcnt(0)" ::: "memory")
#define SBAR()   __builtin_amdgcn_s_barrier()
#define SCHED0() __builtin_amdgcn_sched_barrier(0)

static __device__ __forceinline__ unsigned short f2bf(float f) {
    unsigned int u = __builtin_bit_cast(unsigned int, f);
    u += 0x7FFFu + ((u >> 16) & 1u);   // round-to-nearest-even
    return (unsigned short)(u >> 16);
}

static __device__ __forceinline__ unsigned int cvt_pk_bf16(float lo, float hi) {
    unsigned int w;
    asm("v_cvt_pk_bf16_f32 %0, %1, %2" : "=v"(w) : "v"(lo), "v"(hi));
    return w;
}

static __device__ __forceinline__ void gld_lds16(const void* g, void* l) {
    __builtin_amdgcn_global_load_lds(
        (const __attribute__((address_space(1))) void*)g,
        (__attribute__((address_space(3))) void*)l, 16, 0, 0);
}

static __device__ __forceinline__ f32x4 mfma_bf16(bf16x8 a, bf16x8 b, f32x4 c) {
    return __builtin_amdgcn_mfma_f32_16x16x32_bf16(a, b, c, 0, 0, 0);
}

static __device__ __forceinline__ f32x4 fmax4(f32x4 a, f32x4 b) {
    f32x4 r;
    r[0] = fmaxf(a[0], b[0]); r[1] = fmaxf(a[1], b[1]);
    r[2] = fmaxf(a[2], b[2]); r[3] = fmaxf(a[3], b[3]);
    return r;
}

// ---------------- fp32 -> bf16 conversion ----------------
__global__ __launch_bounds__(256) void cvt_kernel(const float* __restrict__ in,
                                                  unsigned short* __restrict__ out,
                                                  int n) {
    int i = (blockIdx.x * 256 + threadIdx.x) * 4;
    if (i >= n) return;
    float4 v = *(const float4*)(in + i);
    us4v o;
    o[0] = f2bf(v.x); o[1] = f2bf(v.y); o[2] = f2bf(v.z); o[3] = f2bf(v.w);
    *(us4v*)(out + i) = o;
}

// 4 weight matrices (1M elements each) in one launch
__global__ __launch_bounds__(256) void cvt4_kernel(const float* __restrict__ a,
                                                   const float* __restrict__ b,
                                                   const float* __restrict__ c,
                                                   const float* __restrict__ d,
                                                   unsigned short* __restrict__ oa,
                                                   unsigned short* __restrict__ ob,
                                                   unsigned short* __restrict__ oc,
                                                   unsigned short* __restrict__ od) {
    const int sel = blockIdx.x >> 10;
    const float* in = sel == 0 ? a : sel == 1 ? b : sel == 2 ? c : d;
    unsigned short* out = sel == 0 ? oa : sel == 1 ? ob : sel == 2 ? oc : od;
    int i = ((blockIdx.x & 1023) * 256 + threadIdx.x) * 4;
    float4 v = *(const float4*)(in + i);
    us4v o;
    o[0] = f2bf(v.x); o[1] = f2bf(v.y); o[2] = f2bf(v.z); o[3] = f2bf(v.w);
    *(us4v*)(out + i) = o;
}

// ---------------- GEMM 128x128, BK=32, LDS dbuf + counted vmcnt: fused QK ----------------
__global__ __launch_bounds__(256) void gemm_qk(const unsigned short* __restrict__ A,
                                               const unsigned short* __restrict__ Bm,
                                               const float* __restrict__ bias0,
                                               const float* __restrict__ bias1,
                                               unsigned short* __restrict__ out,
                                               float scale) {
    __shared__ unsigned short As[2][128 * 32];
    __shared__ unsigned short Bs[2][128 * 32];
    const int K = Cv;

    const int tid  = threadIdx.x;
    const int lane = tid & 63;
    const int w    = tid >> 6;
    const int wr   = w >> 1, wc = w & 1;
    const int m0   = blockIdx.y * 128;
    const int n0   = blockIdx.x * 128;
    const int l16  = lane & 15;
    const int lk8  = (lane >> 4) * 8;

    f32x4 acc[4][4] = {};
    const int srow = tid >> 2;
    const int skc  = (tid & 3) * 8;

    auto stageAB = [&](int buf, int k0) {
        gld_lds16(A  + (size_t)(m0 + srow)      * K + k0 + skc, &As[buf][(size_t)tid * 8]);
        gld_lds16(A  + (size_t)(m0 + srow + 64) * K + k0 + skc, &As[buf][(size_t)(tid + 256) * 8]);
        gld_lds16(Bm + (size_t)(n0 + srow)      * K + k0 + skc, &Bs[buf][(size_t)tid * 8]);
        gld_lds16(Bm + (size_t)(n0 + srow + 64) * K + k0 + skc, &Bs[buf][(size_t)(tid + 256) * 8]);
    };

    int buf = 0;
    stageAB(0, 0);
    for (int k0 = 0; k0 < K; k0 += 32) {
        if (k0 + 32 < K) { stageAB(buf ^ 1, k0 + 32); VMCNT(4); }
        else             VMCNT(0);
        SBAR(); SCHED0();

        bf16x8 af[4], bf[4];
#pragma unroll
        for (int mf = 0; mf < 4; ++mf)
            af[mf] = *(const bf16x8*)&As[buf][(wr * 64 + mf * 16 + l16) * 32 + lk8];
#pragma unroll
        for (int nf = 0; nf < 4; ++nf)
            bf[nf] = *(const bf16x8*)&Bs[buf][(wc * 64 + nf * 16 + l16) * 32 + lk8];
#pragma unroll
        for (int mf = 0; mf < 4; ++mf)
#pragma unroll
            for (int nf = 0; nf < 4; ++nf)
                acc[mf][nf] = mfma_bf16(af[mf], bf[nf], acc[mf][nf]);

        LGKM0(); SBAR();
        buf ^= 1;
    }

#pragma unroll
    for (int mf = 0; mf < 4; ++mf)
#pragma unroll
        for (int nf = 0; nf < 4; ++nf)
#pragma unroll
            for (int r = 0; r < 4; ++r) {
                int m = m0 + wr * 64 + mf * 16 + (lane >> 4) * 4 + r;
                int n = n0 + wc * 64 + nf * 16 + l16;
                int sel = n >> 10, ch = n & 1023;
                float bia = sel ? bias1[ch] : bias0[ch];
                float v = (acc[mf][nf][r] + bia) * (sel ? 1.0f : scale);
                int b = m >> 11, t = m & (Tv - 1);
                int h = ch >> 6, d = ch & (HDv - 1);
                out[(size_t)sel * 4194304 +
                    (((size_t)(b * Hv + h)) * Tv + t) * HDv + d] = f2bf(v);
            }
}

// ---------------- GEMM 128(M)x64(N), BK=64, XOR-swizzled LDS dbuf ----------------
// mode 1: out fp32 [m*N+n], bias0[n].  mode 2: out bf16 V^T, bias0[m].
__global__ __launch_bounds__(256) void gemm_64(const unsigned short* __restrict__ A,
                                               const unsigned short* __restrict__ Bm,
                                               const float* __restrict__ bias0,
                                               void* __restrict__ out,
                                               int N, int K, int mode) {
    __shared__ unsigned short As[2][128 * 64];
    __shared__ unsigned short Bs[2][64 * 64];

    const int tid  = threadIdx.x;
    const int lane = tid & 63;
    const int w    = tid >> 6;
    const int wr   = w >> 1, wc = w & 1;
    const int m0   = blockIdx.y * 128;
    const int n0   = blockIdx.x * 64;
    const int l16  = lane & 15;
    const int lk   = (lane >> 4);

    f32x4 acc[4][2] = {};

    auto stageAB = [&](int buf, int k0) {
#pragma unroll
        for (int i = 0; i < 4; ++i) {
            int ch = i * 256 + tid, r = ch >> 3, cs = ch & 7, c = cs ^ (r & 7);
            gld_lds16(A + (size_t)(m0 + r) * K + k0 + c * 8, &As[buf][(size_t)ch * 8]);
        }
#pragma unroll
        for (int i = 0; i < 2; ++i) {
            int ch = i * 256 + tid, r = ch >> 3, cs = ch & 7, c = cs ^ (r & 7);
            gld_lds16(Bm + (size_t)(n0 + r) * K + k0 + c * 8, &Bs[buf][(size_t)ch * 8]);
        }
    };

    int buf = 0;
    stageAB(0, 0);
    for (int k0 = 0; k0 < K; k0 += 64) {
        if (k0 + 64 < K) { stageAB(buf ^ 1, k0 + 64); VMCNT(6); }
        else             VMCNT(0);
        SBAR(); SCHED0();

#pragma unroll
        for (int ks = 0; ks < 2; ++ks) {
            bf16x8 af[4], bf[2];
#pragma unroll
            for (int mf = 0; mf < 4; ++mf) {
                int row = wr * 64 + mf * 16 + l16;
                af[mf] = *(const bf16x8*)&As[buf][(row * 8 + ((ks * 4 + lk) ^ (row & 7))) * 8];
            }
#pragma unroll
            for (int nf = 0; nf < 2; ++nf) {
                int row = wc * 32 + nf * 16 + l16;
                bf[nf] = *(const bf16x8*)&Bs[buf][(row * 8 + ((ks * 4 + lk) ^ (row & 7))) * 8];
            }
#pragma unroll
            for (int mf = 0; mf < 4; ++mf)
#pragma unroll
                for (int nf = 0; nf < 2; ++nf)
                    acc[mf][nf] = mfma_bf16(af[mf], bf[nf], acc[mf][nf]);
        }

        LGKM0(); SBAR();
        buf ^= 1;
    }

#pragma unroll
    for (int mf = 0; mf < 4; ++mf)
#pragma unroll
        for (int nf = 0; nf < 2; ++nf)
#pragma unroll
            for (int r = 0; r < 4; ++r) {
                int m = m0 + wr * 64 + mf * 16 + (lane >> 4) * 4 + r;
                int n = n0 + wc * 32 + nf * 16 + l16;
                if (mode == 2) {
                    float v = acc[mf][nf][r] + bias0[m];
                    ((unsigned short*)out)[((size_t)(n >> 11) * 1024 + m) * Tv + (n & (Tv - 1))] = f2bf(v);
                } else {
                    ((float*)out)[(size_t)m * N + n] = acc[mf][nf][r] + bias0[n];
                }
            }
}

// ---------------- causal flash attention (block-staged K, counted-vmcnt pipeline) ----------------
// Block = 4 waves = one 64-q-row tile; 1024 blocks (4/CU co-resident).
// Pipeline: issue stage(next) -> vmcnt(2) [waits only PREVIOUS tile's loads] ->
// raw s_barrier -> QK/softmax/PV -> lgkmcnt(0)+s_barrier. Prefetch latency hides
// under the previous iteration's compute instead of draining at every barrier.
__global__ __launch_bounds__(256) void attn_kernel(const unsigned short* __restrict__ q,
                                                   const unsigned short* __restrict__ k,
                                                   const unsigned short* __restrict__ vt,
                                                   unsigned short* __restrict__ y) {
    __shared__ __align__(16) unsigned short Ks[2][64 * 64];   // [buf][r*8 + cs chunks of 16B]
    __shared__ __align__(16) unsigned short Pb[4][16 * 72];   // 72 shorts/row

    const int tid  = threadIdx.x;
    const int lane = tid & 63;
    const int w    = tid >> 6;
    const int l16  = lane & 15;
    const int lk   = lane >> 4;

    const int lb   = blockIdx.x;
    const int xcd  = lb & 7;
    const int rest = lb >> 3;                 // 0..127
    const int bh   = xcd * 4 + (rest >> 5);
    const int tl   = rest & 31;
    const int tile = ((rest >> 5) & 1) ? (31 - tl) : tl;   // complementary pairing

    const int b = bh >> 4, h = bh & (Hv - 1);
    const int qr0 = tile * 64 + w * 16;       // this wave's first q row
    const int qg  = qr0 + l16;
    const size_t head_off = (size_t)bh * (Tv * HDv);
    const unsigned short* kpb = k  + head_off;
    const unsigned short* vpb = vt + head_off;   // [HD][T]
    unsigned short* pb = &Pb[w][0];
    const int prow = l16 * 72;

    // Q as B-fragment: col=q (l16), contraction = d
    bf16x8 qf0, qf1;
    {
        const unsigned short* qp = q + head_off + (size_t)qg * HDv + lk * 8;
        qf0 = *(const bf16x8*)qp;
        qf1 = *(const bf16x8*)(qp + 32);
    }

    f32x4 acc[4] = {};           // O^T: acc[nt], row d = nt*16+lk*4+r, col q = l16
    float m = -1e38f, l = 0.f;
    const int nkt = tile + 1;    // 64-wide K tiles

    auto stage = [&](int buf, int kk0) {
#pragma unroll
        for (int i = 0; i < 2; ++i) {
            int ch = (w * 2 + i) * 64 + lane;
            int r  = ch >> 3, cs = ch & 7;
            int c  = cs ^ (r & 7);
            gld_lds16(kpb + (size_t)(kk0 + r) * HDv + c * 8, &Ks[buf][ch * 8]);
        }
    };

    int cur = 0;
    stage(0, 0);

    for (int j = 0; j < nkt; ++j) {
        const int kk0 = j * 64;
        if (j + 1 < nkt) { stage(cur ^ 1, kk0 + 64); VMCNT(2); }
        else             VMCNT(0);
        SBAR(); SCHED0();

        // S^T = K Q^T from LDS
        f32x4 s[4];
        __builtin_amdgcn_s_setprio(1);
#pragma unroll
        for (int ct = 0; ct < 4; ++ct) {
            const int rr = ct * 16 + l16;
            bf16x8 k0 = *(const bf16x8*)&Ks[cur][(rr * 8 + (lk       ^ (rr & 7))) * 8];
            bf16x8 k1 = *(const bf16x8*)&Ks[cur][(rr * 8 + ((4 + lk) ^ (rr & 7))) * 8];
            f32x4 z = {};
            z = mfma_bf16(k0, qf0, z);
            z = mfma_bf16(k1, qf1, z);
            s[ct] = z;
        }
        __builtin_amdgcn_s_setprio(0);

        // V^T fragments from global, issued early
        bf16x8 vf[4][2];
#pragma unroll
        for (int nt = 0; nt < 4; ++nt)
#pragma unroll
            for (int kh = 0; kh < 2; ++kh)
                vf[nt][kh] = *(const bf16x8*)(vpb + (size_t)(nt * 16 + l16) * Tv + kk0 + kh * 32 + lk * 8);

        // causal mask (diagonal tile only)
        if (kk0 + 63 > qr0) {
#pragma unroll
            for (int ct = 0; ct < 4; ++ct) {
                const int kb2 = kk0 + ct * 16 + lk * 4;
#pragma unroll
                for (int r = 0; r < 4; ++r)
                    if (kb2 + r > qg) s[ct][r] = -1e38f;
            }
        }

        // online softmax (base-2; scale folded into q)
        f32x4 t0 = fmax4(fmax4(s[0], s[1]), fmax4(s[2], s[3]));
        float pm = fmaxf(fmaxf(t0[0], t0[1]), fmaxf(t0[2], t0[3]));
        pm = fmaxf(pm, __shfl_xor(pm, 16));
        pm = fmaxf(pm, __shfl_xor(pm, 32));

        if (__all(pm - m <= 8.0f)) {          // defer-max (T13)
#pragma unroll
            for (int ct = 0; ct < 4; ++ct)
#pragma unroll
                for (int r = 0; r < 4; ++r)
                    s[ct][r] = __builtin_exp2f(s[ct][r] - m);
        } else {
            const float mnew  = fmaxf(m, pm);
            const float alpha = __builtin_exp2f(m - mnew);
#pragma unroll
            for (int ct = 0; ct < 4; ++ct)
#pragma unroll
                for (int r = 0; r < 4; ++r)
                    s[ct][r] = __builtin_exp2f(s[ct][r] - mnew);
            l *= alpha;
#pragma unroll
            for (int nt = 0; nt < 4; ++nt)
                acc[nt] *= alpha;
            m = mnew;
        }

        f32x4 u0 = (s[0] + s[1]) + (s[2] + s[3]);
        float psum = (u0[0] + u0[1]) + (u0[2] + u0[3]);
        psum += __shfl_xor(psum, 16);
        psum += __shfl_xor(psum, 32);
        l += psum;

        // P^T -> LDS rows=q (wave-private buffer)
#pragma unroll
        for (int ct = 0; ct < 4; ++ct) {
            uint2 wv;
            wv.x = cvt_pk_bf16(s[ct][0], s[ct][1]);
            wv.y = cvt_pk_bf16(s[ct][2], s[ct][3]);
            *(uint2*)&pb[prow + ct * 16 + lk * 4] = wv;
        }

        // O^T += V^T * P^T
        __builtin_amdgcn_s_setprio(1);
#pragma unroll
        for (int kh = 0; kh < 2; ++kh) {
            union { us4v p[2]; bf16x8 f; } u;
            u.p[0] = *(const us4v*)&pb[prow + kh * 32 + lk * 8];
            u.p[1] = *(const us4v*)&pb[prow + kh * 32 + lk * 8 + 4];
#pragma unroll
            for (int nt = 0; nt < 4; ++nt)
                acc[nt] = mfma_bf16(vf[nt][kh], u.f, acc[nt]);
        }
        __builtin_amdgcn_s_setprio(0);

        LGKM0(); SBAR();          // all waves done with Ks[cur]; safe to overwrite next iter
        cur ^= 1;
    }

    // epilogue
    const float rl = 1.0f / l;
    const size_t ybase = ((size_t)(b * Tv + qg)) * Cv + h * HDv + lk * 4;
#pragma unroll
    for (int nt = 0; nt < 4; ++nt) {
        uint2 wv;
        wv.x = cvt_pk_bf16(acc[nt][0] * rl, acc[nt][1] * rl);
        wv.y = cvt_pk_bf16(acc[nt][2] * rl, acc[nt][3] * rl);
        *(uint2*)&y[ybase + nt * 16] = wv;
    }
}

extern "C" void kernel_launch(void* const* d_in, const int* in_sizes, int n_in,
                              void* d_out, int out_size, void* d_ws, size_t ws_size,
                              hipStream_t stream) {
    const float* x  = (const float*)d_in[0];
    const float* Wk = (const float*)d_in[1];
    const float* bk = (const float*)d_in[2];
    const float* Wq = (const float*)d_in[3];
    const float* bq = (const float*)d_in[4];
    const float* Wv = (const float*)d_in[5];
    const float* bv = (const float*)d_in[6];
    const float* Wp = (const float*)d_in[7];
    const float* bp = (const float*)d_in[8];

    // workspace layout (ushorts); total 40 MB
    unsigned short* ws   = (unsigned short*)d_ws;
    unsigned short* xb   = ws;                   // 4194304 (reused as yb)
    unsigned short* wqkb = xb   + 4194304;       // 2097152: Wq rows then Wk rows
    unsigned short* wvb  = wqkb + 2097152;       // 1048576
    unsigned short* wpb  = wvb  + 1048576;       // 1048576
    unsigned short* qb   = wpb  + 1048576;       // 4194304, head-split, pre-scaled
    unsigned short* kb   = qb   + 4194304;       // 4194304, head-split (qb+4194304!)
    unsigned short* vtb  = kb   + 4194304;       // 4194304, V^T [B*H][HD][T]
    unsigned short* yb   = xb;                   // reuse: x dead after QKV GEMMs
    (void)kb;

    cvt_kernel<<<4096, 256, 0, stream>>>(x, xb, 4194304);
    cvt4_kernel<<<4096, 256, 0, stream>>>(Wq, Wk, Wv, Wp,
                                          wqkb, wqkb + 1048576, wvb, wpb);

    // fused Q+K projection: 128x128 tiles, grid (16,32) = 512 blocks (2/CU)
    dim3 gqk(2048 / 128, (Bv * Tv) / 128);
    gemm_qk<<<gqk, 256, 0, stream>>>(xb, wqkb, bq, bk, qb, 0.125f * LOG2E);
    // V^T: C[c][tok] = sum_k Wv[c][k]*x[tok][k]; 128x64, BK=64, grid (64,8)=512
    dim3 gv((Bv * Tv) / 64, Cv / 128);
    gemm_64<<<gv, 256, 0, stream>>>(wvb, xb, bv, vtb, Bv * Tv, Cv, 2);

    attn_kernel<<<1024, 256, 0, stream>>>(qb, kb, vtb, yb);

    // output projection: 128x64, BK=64, grid (16,32)=512
    dim3 gp(Cv / 64, (Bv * Tv) / 128);
    gemm_64<<<gp, 256, 0, stream>>>(yb, wpb, bp, d_out, Cv, Cv, 1);
}

// Round 9
// 142.145 us; speedup vs baseline: 1.3000x; 1.3000x over previous
//
#include <hip/hip_runtime.h>
#include <stdint.h>

// Problem constants
#define Bv  2
#define Tv  2048
#define Cv  1024
#define Hv  16
#define HDv 64
#define LOG2E 1.44269504088896340736f

typedef __bf16 bf16x8 __attribute__((ext_vector_type(8)));
typedef float f32x4 __attribute__((ext_vector_type(4)));
typedef unsigned short us4v __attribute__((ext_vector_type(4)));

#define VMCNT(n) asm volatile("s_waitcnt vmcnt(" #n ")" ::: "memory")
#define LGKM0()  asm volatile("s_waitcnt lgkmcnt(0)" ::: "memory")
#define SBAR()   __builtin_amdgcn_s_barrier()
#define SCHED0() __builtin_amdgcn_sched_barrier(0)

static __device__ __forceinline__ unsigned short f2bf(float f) {
    unsigned int u = __builtin_bit_cast(unsigned int, f);
    u += 0x7FFFu + ((u >> 16) & 1u);   // round-to-nearest-even
    return (unsigned short)(u >> 16);
}

static __device__ __forceinline__ unsigned int cvt_pk_bf16(float lo, float hi) {
    unsigned int w;
    asm("v_cvt_pk_bf16_f32 %0, %1, %2" : "=v"(w) : "v"(lo), "v"(hi));
    return w;
}

static __device__ __forceinline__ void gld_lds16(const void* g, void* l) {
    __builtin_amdgcn_global_load_lds(
        (const __attribute__((address_space(1))) void*)g,
        (__attribute__((address_space(3))) void*)l, 16, 0, 0);
}

static __device__ __forceinline__ f32x4 mfma_bf16(bf16x8 a, bf16x8 b, f32x4 c) {
    return __builtin_amdgcn_mfma_f32_16x16x32_bf16(a, b, c, 0, 0, 0);
}

static __device__ __forceinline__ f32x4 fmax4(f32x4 a, f32x4 b) {
    f32x4 r;
    r[0] = fmaxf(a[0], b[0]); r[1] = fmaxf(a[1], b[1]);
    r[2] = fmaxf(a[2], b[2]); r[3] = fmaxf(a[3], b[3]);
    return r;
}

// ---------------- fp32 -> bf16 conversion ----------------
__global__ __launch_bounds__(256) void cvt_kernel(const float* __restrict__ in,
                                                  unsigned short* __restrict__ out,
                                                  int n) {
    int i = (blockIdx.x * 256 + threadIdx.x) * 4;
    if (i >= n) return;
    float4 v = *(const float4*)(in + i);
    us4v o;
    o[0] = f2bf(v.x); o[1] = f2bf(v.y); o[2] = f2bf(v.z); o[3] = f2bf(v.w);
    *(us4v*)(out + i) = o;
}

// 4 weight matrices (1M elements each) in one launch
__global__ __launch_bounds__(256) void cvt4_kernel(const float* __restrict__ a,
                                                   const float* __restrict__ b,
                                                   const float* __restrict__ c,
                                                   const float* __restrict__ d,
                                                   unsigned short* __restrict__ oa,
                                                   unsigned short* __restrict__ ob,
                                                   unsigned short* __restrict__ oc,
                                                   unsigned short* __restrict__ od) {
    const int sel = blockIdx.x >> 10;
    const float* in = sel == 0 ? a : sel == 1 ? b : sel == 2 ? c : d;
    unsigned short* out = sel == 0 ? oa : sel == 1 ? ob : sel == 2 ? oc : od;
    int i = ((blockIdx.x & 1023) * 256 + threadIdx.x) * 4;
    float4 v = *(const float4*)(in + i);
    us4v o;
    o[0] = f2bf(v.x); o[1] = f2bf(v.y); o[2] = f2bf(v.z); o[3] = f2bf(v.w);
    *(us4v*)(out + i) = o;
}

// ---------------- GEMM 128x128, BK=32, LDS dbuf + counted vmcnt: fused QK ----------------
__global__ __launch_bounds__(256) void gemm_qk(const unsigned short* __restrict__ A,
                                               const unsigned short* __restrict__ Bm,
                                               const float* __restrict__ bias0,
                                               const float* __restrict__ bias1,
                                               unsigned short* __restrict__ out,
                                               float scale) {
    __shared__ unsigned short As[2][128 * 32];
    __shared__ unsigned short Bs[2][128 * 32];
    const int K = Cv;

    const int tid  = threadIdx.x;
    const int lane = tid & 63;
    const int w    = tid >> 6;
    const int wr   = w >> 1, wc = w & 1;
    const int m0   = blockIdx.y * 128;
    const int n0   = blockIdx.x * 128;
    const int l16  = lane & 15;
    const int lk8  = (lane >> 4) * 8;

    f32x4 acc[4][4] = {};
    const int srow = tid >> 2;
    const int skc  = (tid & 3) * 8;

    auto stageAB = [&](int buf, int k0) {
        gld_lds16(A  + (size_t)(m0 + srow)      * K + k0 + skc, &As[buf][(size_t)tid * 8]);
        gld_lds16(A  + (size_t)(m0 + srow + 64) * K + k0 + skc, &As[buf][(size_t)(tid + 256) * 8]);
        gld_lds16(Bm + (size_t)(n0 + srow)      * K + k0 + skc, &Bs[buf][(size_t)tid * 8]);
        gld_lds16(Bm + (size_t)(n0 + srow + 64) * K + k0 + skc, &Bs[buf][(size_t)(tid + 256) * 8]);
    };

    int buf = 0;
    stageAB(0, 0);
    for (int k0 = 0; k0 < K; k0 += 32) {
        if (k0 + 32 < K) { stageAB(buf ^ 1, k0 + 32); VMCNT(4); }
        else             VMCNT(0);
        SBAR(); SCHED0();

        bf16x8 af[4], bf[4];
#pragma unroll
        for (int mf = 0; mf < 4; ++mf)
            af[mf] = *(const bf16x8*)&As[buf][(wr * 64 + mf * 16 + l16) * 32 + lk8];
#pragma unroll
        for (int nf = 0; nf < 4; ++nf)
            bf[nf] = *(const bf16x8*)&Bs[buf][(wc * 64 + nf * 16 + l16) * 32 + lk8];
#pragma unroll
        for (int mf = 0; mf < 4; ++mf)
#pragma unroll
            for (int nf = 0; nf < 4; ++nf)
                acc[mf][nf] = mfma_bf16(af[mf], bf[nf], acc[mf][nf]);

        LGKM0(); SBAR();
        buf ^= 1;
    }

#pragma unroll
    for (int mf = 0; mf < 4; ++mf)
#pragma unroll
        for (int nf = 0; nf < 4; ++nf)
#pragma unroll
            for (int r = 0; r < 4; ++r) {
                int m = m0 + wr * 64 + mf * 16 + (lane >> 4) * 4 + r;
                int n = n0 + wc * 64 + nf * 16 + l16;
                int sel = n >> 10, ch = n & 1023;
                float bia = sel ? bias1[ch] : bias0[ch];
                float v = (acc[mf][nf][r] + bia) * (sel ? 1.0f : scale);
                int b = m >> 11, t = m & (Tv - 1);
                int h = ch >> 6, d = ch & (HDv - 1);
                out[(size_t)sel * 4194304 +
                    (((size_t)(b * Hv + h)) * Tv + t) * HDv + d] = f2bf(v);
            }
}

// ---------------- GEMM 128(M)x64(N), BK=64, XOR-swizzled LDS dbuf ----------------
// mode 1: out fp32 [m*N+n], bias0[n].  mode 2: out bf16 V^T, bias0[m].
__global__ __launch_bounds__(256) void gemm_64(const unsigned short* __restrict__ A,
                                               const unsigned short* __restrict__ Bm,
                                               const float* __restrict__ bias0,
                                               void* __restrict__ out,
                                               int N, int K, int mode) {
    __shared__ unsigned short As[2][128 * 64];
    __shared__ unsigned short Bs[2][64 * 64];

    const int tid  = threadIdx.x;
    const int lane = tid & 63;
    const int w    = tid >> 6;
    const int wr   = w >> 1, wc = w & 1;
    const int m0   = blockIdx.y * 128;
    const int n0   = blockIdx.x * 64;
    const int l16  = lane & 15;
    const int lk   = (lane >> 4);

    f32x4 acc[4][2] = {};

    auto stageAB = [&](int buf, int k0) {
#pragma unroll
        for (int i = 0; i < 4; ++i) {
            int ch = i * 256 + tid, r = ch >> 3, cs = ch & 7, c = cs ^ (r & 7);
            gld_lds16(A + (size_t)(m0 + r) * K + k0 + c * 8, &As[buf][(size_t)ch * 8]);
        }
#pragma unroll
        for (int i = 0; i < 2; ++i) {
            int ch = i * 256 + tid, r = ch >> 3, cs = ch & 7, c = cs ^ (r & 7);
            gld_lds16(Bm + (size_t)(n0 + r) * K + k0 + c * 8, &Bs[buf][(size_t)ch * 8]);
        }
    };

    int buf = 0;
    stageAB(0, 0);
    for (int k0 = 0; k0 < K; k0 += 64) {
        if (k0 + 64 < K) { stageAB(buf ^ 1, k0 + 64); VMCNT(6); }
        else             VMCNT(0);
        SBAR(); SCHED0();

#pragma unroll
        for (int ks = 0; ks < 2; ++ks) {
            bf16x8 af[4], bf[2];
#pragma unroll
            for (int mf = 0; mf < 4; ++mf) {
                int row = wr * 64 + mf * 16 + l16;
                af[mf] = *(const bf16x8*)&As[buf][(row * 8 + ((ks * 4 + lk) ^ (row & 7))) * 8];
            }
#pragma unroll
            for (int nf = 0; nf < 2; ++nf) {
                int row = wc * 32 + nf * 16 + l16;
                bf[nf] = *(const bf16x8*)&Bs[buf][(row * 8 + ((ks * 4 + lk) ^ (row & 7))) * 8];
            }
#pragma unroll
            for (int mf = 0; mf < 4; ++mf)
#pragma unroll
                for (int nf = 0; nf < 2; ++nf)
                    acc[mf][nf] = mfma_bf16(af[mf], bf[nf], acc[mf][nf]);
        }

        LGKM0(); SBAR();
        buf ^= 1;
    }

#pragma unroll
    for (int mf = 0; mf < 4; ++mf)
#pragma unroll
        for (int nf = 0; nf < 2; ++nf)
#pragma unroll
            for (int r = 0; r < 4; ++r) {
                int m = m0 + wr * 64 + mf * 16 + (lane >> 4) * 4 + r;
                int n = n0 + wc * 32 + nf * 16 + l16;
                if (mode == 2) {
                    float v = acc[mf][nf][r] + bias0[m];
                    ((unsigned short*)out)[((size_t)(n >> 11) * 1024 + m) * Tv + (n & (Tv - 1))] = f2bf(v);
                } else {
                    ((float*)out)[(size_t)m * N + n] = acc[mf][nf][r] + bias0[n];
                }
            }
}

// ---------------- causal flash attention (balanced tile-pair blocks, K+V staged) --------
// Block = 4 waves = one 64-q-row tile, TWO phases: tile p, then tile 31-p.
// Work per block = (p+1) + (32-p) = 33 kt-units EXACTLY -> perfectly balanced for any
// dispatch order. 512 blocks (2/CU). K AND V^T staged to LDS via gld_lds (4 loads/wave
// per iter), double-buffered, counted vmcnt(4), source-side XOR swizzle both operands.
__global__ __launch_bounds__(256) void attn_kernel(const unsigned short* __restrict__ q,
                                                   const unsigned short* __restrict__ k,
                                                   const unsigned short* __restrict__ vt,
                                                   unsigned short* __restrict__ y) {
    __shared__ __align__(16) unsigned short KVs[2][2][64 * 64];  // [buf][K/V][r*8+cs chunks]
    __shared__ __align__(16) unsigned short Pb[4][16 * 72];      // 72 shorts/row

    const int tid  = threadIdx.x;
    const int lane = tid & 63;
    const int w    = tid >> 6;
    const int l16  = lane & 15;
    const int lk   = lane >> 4;

    // 512 blocks: xcd = lb&7, rest 0..63 -> head (rest>>4), pair p (rest&15)
    const int lb   = blockIdx.x;
    const int xcd  = lb & 7;
    const int rest = lb >> 3;
    const int bh   = xcd * 4 + (rest >> 4);
    const int p    = rest & 15;

    const int b = bh >> 4, h = bh & (Hv - 1);
    const size_t head_off = (size_t)bh * (Tv * HDv);
    const unsigned short* kpb = k  + head_off;
    const unsigned short* vpb = vt + head_off;   // [HD][T]
    unsigned short* pb = &Pb[w][0];
    const int prow = l16 * 72;
    const int rc   = l16 & 7;                    // row&7 for all LDS reads (rows = x*16+l16)

    auto stage = [&](int buf, int kk0) {
#pragma unroll
        for (int i = 0; i < 2; ++i) {
            int ch = (w * 2 + i) * 64 + lane;
            int r  = ch >> 3, cs = ch & 7;
            int c  = cs ^ (r & 7);
            gld_lds16(kpb + (size_t)(kk0 + r) * HDv + c * 8, &KVs[buf][0][ch * 8]);
            gld_lds16(vpb + (size_t)r * Tv + kk0 + c * 8,    &KVs[buf][1][ch * 8]);
        }
    };

    for (int ph = 0; ph < 2; ++ph) {
        const int tile = ph ? (31 - p) : p;
        const int qr0  = tile * 64 + w * 16;
        const int qg   = qr0 + l16;
        const int nkt  = tile + 1;

        // Q as B-fragment: col=q (l16), contraction = d
        bf16x8 qf0, qf1;
        {
            const unsigned short* qp = q + head_off + (size_t)qg * HDv + lk * 8;
            qf0 = *(const bf16x8*)qp;
            qf1 = *(const bf16x8*)(qp + 32);
        }

        f32x4 acc[4] = {};        // O^T: acc[nt], row d = nt*16+lk*4+r, col q = l16
        float m = -1e38f, l = 0.f;

        int cur = 0;
        stage(0, 0);

        for (int j = 0; j < nkt; ++j) {
            const int kk0 = j * 64;
            if (j + 1 < nkt) { stage(cur ^ 1, kk0 + 64); VMCNT(4); }
            else             VMCNT(0);
            SBAR(); SCHED0();

            const unsigned short* Ks = &KVs[cur][0][0];
            const unsigned short* Vs = &KVs[cur][1][0];

            // S^T = K Q^T from LDS
            f32x4 s[4];
            __builtin_amdgcn_s_setprio(1);
#pragma unroll
            for (int ct = 0; ct < 4; ++ct) {
                const int rr = ct * 16 + l16;
                bf16x8 k0 = *(const bf16x8*)&Ks[(rr * 8 + (lk       ^ rc)) * 8];
                bf16x8 k1 = *(const bf16x8*)&Ks[(rr * 8 + ((4 + lk) ^ rc)) * 8];
                f32x4 z = {};
                z = mfma_bf16(k0, qf0, z);
                z = mfma_bf16(k1, qf1, z);
                s[ct] = z;
            }
            __builtin_amdgcn_s_setprio(0);

            // V^T fragments from LDS (row d = nt*16+l16, chunk kh*4+lk, same swizzle)
            bf16x8 vf[4][2];
#pragma unroll
            for (int nt = 0; nt < 4; ++nt) {
                const int row = nt * 16 + l16;
#pragma unroll
                for (int kh = 0; kh < 2; ++kh)
                    vf[nt][kh] = *(const bf16x8*)&Vs[(row * 8 + ((kh * 4 + lk) ^ rc)) * 8];
            }

            // causal mask (diagonal tile only)
            if (kk0 + 63 > qr0) {
#pragma unroll
                for (int ct = 0; ct < 4; ++ct) {
                    const int kb2 = kk0 + ct * 16 + lk * 4;
#pragma unroll
                    for (int r = 0; r < 4; ++r)
                        if (kb2 + r > qg) s[ct][r] = -1e38f;
                }
            }

            // online softmax (base-2; scale folded into q)
            f32x4 t0 = fmax4(fmax4(s[0], s[1]), fmax4(s[2], s[3]));
            float pm = fmaxf(fmaxf(t0[0], t0[1]), fmaxf(t0[2], t0[3]));
            pm = fmaxf(pm, __shfl_xor(pm, 16));
            pm = fmaxf(pm, __shfl_xor(pm, 32));

            if (__all(pm - m <= 8.0f)) {       // defer-max (T13)
#pragma unroll
                for (int ct = 0; ct < 4; ++ct)
#pragma unroll
                    for (int r = 0; r < 4; ++r)
                        s[ct][r] = __builtin_exp2f(s[ct][r] - m);
            } else {
                const float mnew  = fmaxf(m, pm);
                const float alpha = __builtin_exp2f(m - mnew);
#pragma unroll
                for (int ct = 0; ct < 4; ++ct)
#pragma unroll
                    for (int r = 0; r < 4; ++r)
                        s[ct][r] = __builtin_exp2f(s[ct][r] - mnew);
                l *= alpha;
#pragma unroll
                for (int nt = 0; nt < 4; ++nt)
                    acc[nt] *= alpha;
                m = mnew;
            }

            f32x4 u0 = (s[0] + s[1]) + (s[2] + s[3]);
            float psum = (u0[0] + u0[1]) + (u0[2] + u0[3]);
            psum += __shfl_xor(psum, 16);
            psum += __shfl_xor(psum, 32);
            l += psum;

            // P^T -> LDS rows=q (wave-private buffer)
#pragma unroll
            for (int ct = 0; ct < 4; ++ct) {
                uint2 wv;
                wv.x = cvt_pk_bf16(s[ct][0], s[ct][1]);
                wv.y = cvt_pk_bf16(s[ct][2], s[ct][3]);
                *(uint2*)&pb[prow + ct * 16 + lk * 4] = wv;
            }

            // O^T += V^T * P^T
            __builtin_amdgcn_s_setprio(1);
#pragma unroll
            for (int kh = 0; kh < 2; ++kh) {
                union { us4v pp[2]; bf16x8 f; } u;
                u.pp[0] = *(const us4v*)&pb[prow + kh * 32 + lk * 8];
                u.pp[1] = *(const us4v*)&pb[prow + kh * 32 + lk * 8 + 4];
#pragma unroll
                for (int nt = 0; nt < 4; ++nt)
                    acc[nt] = mfma_bf16(vf[nt][kh], u.f, acc[nt]);
            }
            __builtin_amdgcn_s_setprio(0);

            LGKM0(); SBAR();       // reads of KVs[cur] retired; safe to restage
            cur ^= 1;
        }

        // epilogue: lane-local normalize, packed 8B stores
        const float rl = 1.0f / l;
        const size_t ybase = ((size_t)(b * Tv + qg)) * Cv + h * HDv + lk * 4;
#pragma unroll
        for (int nt = 0; nt < 4; ++nt) {
            uint2 wv;
            wv.x = cvt_pk_bf16(acc[nt][0] * rl, acc[nt][1] * rl);
            wv.y = cvt_pk_bf16(acc[nt][2] * rl, acc[nt][3] * rl);
            *(uint2*)&y[ybase + nt * 16] = wv;
        }
    }
}

extern "C" void kernel_launch(void* const* d_in, const int* in_sizes, int n_in,
                              void* d_out, int out_size, void* d_ws, size_t ws_size,
                              hipStream_t stream) {
    const float* x  = (const float*)d_in[0];
    const float* Wk = (const float*)d_in[1];
    const float* bk = (const float*)d_in[2];
    const float* Wq = (const float*)d_in[3];
    const float* bq = (const float*)d_in[4];
    const float* Wv = (const float*)d_in[5];
    const float* bv = (const float*)d_in[6];
    const float* Wp = (const float*)d_in[7];
    const float* bp = (const float*)d_in[8];

    // workspace layout (ushorts); total 40 MB
    unsigned short* ws   = (unsigned short*)d_ws;
    unsigned short* xb   = ws;                   // 4194304 (reused as yb)
    unsigned short* wqkb = xb   + 4194304;       // 2097152: Wq rows then Wk rows
    unsigned short* wvb  = wqkb + 2097152;       // 1048576
    unsigned short* wpb  = wvb  + 1048576;       // 1048576
    unsigned short* qb   = wpb  + 1048576;       // 4194304, head-split, pre-scaled
    unsigned short* kb   = qb   + 4194304;       // 4194304, head-split (qb+4194304!)
    unsigned short* vtb  = kb   + 4194304;       // 4194304, V^T [B*H][HD][T]
    unsigned short* yb   = xb;                   // reuse: x dead after QKV GEMMs
    (void)kb;

    cvt_kernel<<<4096, 256, 0, stream>>>(x, xb, 4194304);
    cvt4_kernel<<<4096, 256, 0, stream>>>(Wq, Wk, Wv, Wp,
                                          wqkb, wqkb + 1048576, wvb, wpb);

    // fused Q+K projection: 128x128 tiles, grid (16,32) = 512 blocks (2/CU)
    dim3 gqk(2048 / 128, (Bv * Tv) / 128);
    gemm_qk<<<gqk, 256, 0, stream>>>(xb, wqkb, bq, bk, qb, 0.125f * LOG2E);
    // V^T: C[c][tok] = sum_k Wv[c][k]*x[tok][k]; 128x64, BK=64, grid (64,8)=512
    dim3 gv((Bv * Tv) / 64, Cv / 128);
    gemm_64<<<gv, 256, 0, stream>>>(wvb, xb, bv, vtb, Bv * Tv, Cv, 2);

    attn_kernel<<<512, 256, 0, stream>>>(qb, kb, vtb, yb);

    // output projection: 128x64, BK=64, grid (16,32)=512
    dim3 gp(Cv / 64, (Bv * Tv) / 128);
    gemm_64<<<gp, 256, 0, stream>>>(yb, wpb, bp, d_out, Cv, Cv, 1);
}

// Round 10
// 127.940 us; speedup vs baseline: 1.4443x; 1.1110x over previous
//
#include <hip/hip_runtime.h>
#include <stdint.h>

// Problem constants
#define Bv  2
#define Tv  2048
#define Cv  1024
#define Hv  16
#define HDv 64
#define LOG2E 1.44269504088896340736f

typedef __bf16 bf16x8 __attribute__((ext_vector_type(8)));
typedef float f32x4 __attribute__((ext_vector_type(4)));
typedef unsigned short us4v __attribute__((ext_vector_type(4)));
typedef unsigned short us8v __attribute__((ext_vector_type(8)));

#define VMCNT(n) asm volatile("s_waitcnt vmcnt(" #n ")" ::: "memory")
#define LGKM0()  asm volatile("s_waitcnt lgkmcnt(0)" ::: "memory")
#define SBAR()   __builtin_amdgcn_s_barrier()
#define SCHED0() __builtin_amdgcn_sched_barrier(0)

static __device__ __forceinline__ unsigned short f2bf(float f) {
    unsigned int u = __builtin_bit_cast(unsigned int, f);
    u += 0x7FFFu + ((u >> 16) & 1u);   // round-to-nearest-even
    return (unsigned short)(u >> 16);
}

static __device__ __forceinline__ unsigned int cvt_pk_bf16(float lo, float hi) {
    unsigned int w;
    asm("v_cvt_pk_bf16_f32 %0, %1, %2" : "=v"(w) : "v"(lo), "v"(hi));
    return w;
}

static __device__ __forceinline__ void gld_lds16(const void* g, void* l) {
    __builtin_amdgcn_global_load_lds(
        (const __attribute__((address_space(1))) void*)g,
        (__attribute__((address_space(3))) void*)l, 16, 0, 0);
}

static __device__ __forceinline__ f32x4 mfma_bf16(bf16x8 a, bf16x8 b, f32x4 c) {
    return __builtin_amdgcn_mfma_f32_16x16x32_bf16(a, b, c, 0, 0, 0);
}

static __device__ __forceinline__ f32x4 fmax4(f32x4 a, f32x4 b) {
    f32x4 r;
    r[0] = fmaxf(a[0], b[0]); r[1] = fmaxf(a[1], b[1]);
    r[2] = fmaxf(a[2], b[2]); r[3] = fmaxf(a[3], b[3]);
    return r;
}

// ---------------- fp32 -> bf16 conversion ----------------
__global__ __launch_bounds__(256) void cvt_kernel(const float* __restrict__ in,
                                                  unsigned short* __restrict__ out,
                                                  int n) {
    int i = (blockIdx.x * 256 + threadIdx.x) * 4;
    if (i >= n) return;
    float4 v = *(const float4*)(in + i);
    us4v o;
    o[0] = f2bf(v.x); o[1] = f2bf(v.y); o[2] = f2bf(v.z); o[3] = f2bf(v.w);
    *(us4v*)(out + i) = o;
}

// 4 weight matrices (1M elements each) in one launch
__global__ __launch_bounds__(256) void cvt4_kernel(const float* __restrict__ a,
                                                   const float* __restrict__ b,
                                                   const float* __restrict__ c,
                                                   const float* __restrict__ d,
                                                   unsigned short* __restrict__ oa,
                                                   unsigned short* __restrict__ ob,
                                                   unsigned short* __restrict__ oc,
                                                   unsigned short* __restrict__ od) {
    const int sel = blockIdx.x >> 10;
    const float* in = sel == 0 ? a : sel == 1 ? b : sel == 2 ? c : d;
    unsigned short* out = sel == 0 ? oa : sel == 1 ? ob : sel == 2 ? oc : od;
    int i = ((blockIdx.x & 1023) * 256 + threadIdx.x) * 4;
    float4 v = *(const float4*)(in + i);
    us4v o;
    o[0] = f2bf(v.x); o[1] = f2bf(v.y); o[2] = f2bf(v.z); o[3] = f2bf(v.w);
    *(us4v*)(out + i) = o;
}

// ---------------- Fused QKV projection GEMM (1024 blocks) ----------------
// id < 512:  QK part, 128x128 tile, BK=32 dbuf, counted vmcnt. C = x @ [Wq;Wk]^T.
//            n<1024 -> q (scaled, bias bq) at qout; n>=1024 -> k (bias bk) at qout+4M.
// id >= 512: V^T part, 128(chan)x64(tok) tile, BK=32 dbuf. out vt[(tok>>11)*1024+ch][tok&2047].
// Co-resident groups {i,i+256,i+512,i+768} = 2 qk + 2 vt blocks -> balanced CU load.
__global__ __launch_bounds__(256) void gemm_qkv(const unsigned short* __restrict__ X,
                                                const unsigned short* __restrict__ Wqk,
                                                const unsigned short* __restrict__ Wv,
                                                const float* __restrict__ bq,
                                                const float* __restrict__ bk,
                                                const float* __restrict__ bv,
                                                unsigned short* __restrict__ qout,
                                                unsigned short* __restrict__ vtout,
                                                float scale) {
    __shared__ unsigned short As[2][128 * 32];
    __shared__ unsigned short Bs[2][128 * 32];
    const int K = Cv;

    const int tid  = threadIdx.x;
    const int lane = tid & 63;
    const int w    = tid >> 6;
    const int wr   = w >> 1, wc = w & 1;
    const int l16  = lane & 15;
    const int lk8  = (lane >> 4) * 8;
    const int id   = blockIdx.x;

    if (id < 512) {
        const int n0 = (id & 15) * 128;
        const int m0 = (id >> 4) * 128;
        f32x4 acc[4][4] = {};
        const int srow = tid >> 2;
        const int skc  = (tid & 3) * 8;

        auto stageAB = [&](int buf, int k0) {
            gld_lds16(X   + (size_t)(m0 + srow)      * K + k0 + skc, &As[buf][(size_t)tid * 8]);
            gld_lds16(X   + (size_t)(m0 + srow + 64) * K + k0 + skc, &As[buf][(size_t)(tid + 256) * 8]);
            gld_lds16(Wqk + (size_t)(n0 + srow)      * K + k0 + skc, &Bs[buf][(size_t)tid * 8]);
            gld_lds16(Wqk + (size_t)(n0 + srow + 64) * K + k0 + skc, &Bs[buf][(size_t)(tid + 256) * 8]);
        };

        int buf = 0;
        stageAB(0, 0);
        for (int k0 = 0; k0 < K; k0 += 32) {
            if (k0 + 32 < K) { stageAB(buf ^ 1, k0 + 32); VMCNT(4); }
            else             VMCNT(0);
            SBAR(); SCHED0();

            bf16x8 af[4], bf[4];
#pragma unroll
            for (int mf = 0; mf < 4; ++mf)
                af[mf] = *(const bf16x8*)&As[buf][(wr * 64 + mf * 16 + l16) * 32 + lk8];
#pragma unroll
            for (int nf = 0; nf < 4; ++nf)
                bf[nf] = *(const bf16x8*)&Bs[buf][(wc * 64 + nf * 16 + l16) * 32 + lk8];
#pragma unroll
            for (int mf = 0; mf < 4; ++mf)
#pragma unroll
                for (int nf = 0; nf < 4; ++nf)
                    acc[mf][nf] = mfma_bf16(af[mf], bf[nf], acc[mf][nf]);

            LGKM0(); SBAR();
            buf ^= 1;
        }

#pragma unroll
        for (int mf = 0; mf < 4; ++mf)
#pragma unroll
            for (int nf = 0; nf < 4; ++nf)
#pragma unroll
                for (int r = 0; r < 4; ++r) {
                    int m = m0 + wr * 64 + mf * 16 + (lane >> 4) * 4 + r;
                    int n = n0 + wc * 64 + nf * 16 + l16;
                    int sel = n >> 10, ch = n & 1023;
                    float bia = sel ? bk[ch] : bq[ch];
                    float v = (acc[mf][nf][r] + bia) * (sel ? 1.0f : scale);
                    int b = m >> 11, t = m & (Tv - 1);
                    int h = ch >> 6, d = ch & (HDv - 1);
                    qout[(size_t)sel * 4194304 +
                         (((size_t)(b * Hv + h)) * Tv + t) * HDv + d] = f2bf(v);
                }
    } else {
        const int vid = id - 512;
        const int n0 = (vid & 63) * 64;    // token tile
        const int m0 = (vid >> 6) * 128;   // channel tile
        f32x4 acc[4][2] = {};

        auto stageV = [&](int buf, int k0) {
#pragma unroll
            for (int i = 0; i < 2; ++i) {
                int ch = i * 256 + tid, r = ch >> 2, cc = (ch & 3) * 8;
                gld_lds16(Wv + (size_t)(m0 + r) * K + k0 + cc, &As[buf][(size_t)ch * 8]);
            }
            {
                int r = tid >> 2, cc = (tid & 3) * 8;
                gld_lds16(X + (size_t)(n0 + r) * K + k0 + cc, &Bs[buf][(size_t)tid * 8]);
            }
        };

        int buf = 0;
        stageV(0, 0);
        for (int k0 = 0; k0 < K; k0 += 32) {
            if (k0 + 32 < K) { stageV(buf ^ 1, k0 + 32); VMCNT(3); }
            else             VMCNT(0);
            SBAR(); SCHED0();

            bf16x8 af[4], bf[2];
#pragma unroll
            for (int mf = 0; mf < 4; ++mf)
                af[mf] = *(const bf16x8*)&As[buf][(wr * 64 + mf * 16 + l16) * 32 + lk8];
#pragma unroll
            for (int nf = 0; nf < 2; ++nf)
                bf[nf] = *(const bf16x8*)&Bs[buf][(wc * 32 + nf * 16 + l16) * 32 + lk8];
#pragma unroll
            for (int mf = 0; mf < 4; ++mf)
#pragma unroll
                for (int nf = 0; nf < 2; ++nf)
                    acc[mf][nf] = mfma_bf16(af[mf], bf[nf], acc[mf][nf]);

            LGKM0(); SBAR();
            buf ^= 1;
        }

#pragma unroll
        for (int mf = 0; mf < 4; ++mf)
#pragma unroll
            for (int nf = 0; nf < 2; ++nf)
#pragma unroll
                for (int r = 0; r < 4; ++r) {
                    int m = m0 + wr * 64 + mf * 16 + (lane >> 4) * 4 + r;  // channel
                    int n = n0 + wc * 32 + nf * 16 + l16;                  // token
                    float v = acc[mf][nf][r] + bv[m];
                    vtout[((size_t)(n >> 11) * 1024 + m) * Tv + (n & (Tv - 1))] = f2bf(v);
                }
    }
}

// ---------------- GEMM 128(M)x64(N), BK=64, XOR-swizzled LDS dbuf (P projection) ------
__global__ __launch_bounds__(256) void gemm_64(const unsigned short* __restrict__ A,
                                               const unsigned short* __restrict__ Bm,
                                               const float* __restrict__ bias0,
                                               float* __restrict__ out,
                                               int N, int K) {
    __shared__ unsigned short As[2][128 * 64];
    __shared__ unsigned short Bs[2][64 * 64];

    const int tid  = threadIdx.x;
    const int lane = tid & 63;
    const int w    = tid >> 6;
    const int wr   = w >> 1, wc = w & 1;
    const int m0   = blockIdx.y * 128;
    const int n0   = blockIdx.x * 64;
    const int l16  = lane & 15;
    const int lk   = (lane >> 4);

    f32x4 acc[4][2] = {};

    auto stageAB = [&](int buf, int k0) {
#pragma unroll
        for (int i = 0; i < 4; ++i) {
            int ch = i * 256 + tid, r = ch >> 3, cs = ch & 7, c = cs ^ (r & 7);
            gld_lds16(A + (size_t)(m0 + r) * K + k0 + c * 8, &As[buf][(size_t)ch * 8]);
        }
#pragma unroll
        for (int i = 0; i < 2; ++i) {
            int ch = i * 256 + tid, r = ch >> 3, cs = ch & 7, c = cs ^ (r & 7);
            gld_lds16(Bm + (size_t)(n0 + r) * K + k0 + c * 8, &Bs[buf][(size_t)ch * 8]);
        }
    };

    int buf = 0;
    stageAB(0, 0);
    for (int k0 = 0; k0 < K; k0 += 64) {
        if (k0 + 64 < K) { stageAB(buf ^ 1, k0 + 64); VMCNT(6); }
        else             VMCNT(0);
        SBAR(); SCHED0();

#pragma unroll
        for (int ks = 0; ks < 2; ++ks) {
            bf16x8 af[4], bf[2];
#pragma unroll
            for (int mf = 0; mf < 4; ++mf) {
                int row = wr * 64 + mf * 16 + l16;
                af[mf] = *(const bf16x8*)&As[buf][(row * 8 + ((ks * 4 + lk) ^ (row & 7))) * 8];
            }
#pragma unroll
            for (int nf = 0; nf < 2; ++nf) {
                int row = wc * 32 + nf * 16 + l16;
                bf[nf] = *(const bf16x8*)&Bs[buf][(row * 8 + ((ks * 4 + lk) ^ (row & 7))) * 8];
            }
#pragma unroll
            for (int mf = 0; mf < 4; ++mf)
#pragma unroll
                for (int nf = 0; nf < 2; ++nf)
                    acc[mf][nf] = mfma_bf16(af[mf], bf[nf], acc[mf][nf]);
        }

        LGKM0(); SBAR();
        buf ^= 1;
    }

#pragma unroll
    for (int mf = 0; mf < 4; ++mf)
#pragma unroll
        for (int nf = 0; nf < 2; ++nf)
#pragma unroll
            for (int r = 0; r < 4; ++r) {
                int m = m0 + wr * 64 + mf * 16 + (lane >> 4) * 4 + r;
                int n = n0 + wc * 32 + nf * 16 + l16;
                out[(size_t)m * N + n] = acc[mf][nf][r] + bias0[n];
            }
}

// ---------------- causal flash attention: KVBLK=128, sequential pair, MFMA-l ----------
// Block = 4 waves = 64 q-rows; phases (p, 31-p): ceil((p+1)/2)+ceil((32-p)/2) = 17 iters
// per block, CONSTANT -> perfectly balanced. K(128x64), V^T(64x128) staged to LDS
// (dbuf, counted vmcnt(8), source-side XOR pre-swizzle). l computed by ones-MFMA
// (lane-local in acc; rescales with alpha like O) -> no psum tree/shuffles.
// LDS: 32+32+16 = 80 KB -> exactly 2 blocks/CU.
__global__ __launch_bounds__(256) void attn_kernel(const unsigned short* __restrict__ q,
                                                   const unsigned short* __restrict__ k,
                                                   const unsigned short* __restrict__ vt,
                                                   unsigned short* __restrict__ y) {
    __shared__ __align__(16) unsigned short Ks[2][128 * 64];   // rows=k (128), 8 granules, key r&7
    __shared__ __align__(16) unsigned short Vs[2][64 * 128];   // rows=d (64), 16 granules, key (r&7)<<1
    __shared__ __align__(16) unsigned short Pb[4][16 * 128];   // rows=q (16), 16 granules, key (q&7)<<1

    const int tid  = threadIdx.x;
    const int lane = tid & 63;
    const int w    = tid >> 6;
    const int l16  = lane & 15;
    const int lk   = lane >> 4;

    const int lb   = blockIdx.x;               // 512 blocks
    const int xcd  = lb & 7;
    const int rest = lb >> 3;                  // 0..63
    const int bh   = xcd * 4 + (rest >> 4);
    const int p    = rest & 15;

    const int b = bh >> 4, h = bh & (Hv - 1);
    const size_t head_off = (size_t)bh * (Tv * HDv);
    const unsigned short* kpb = k  + head_off;
    const unsigned short* vpb = vt + head_off;     // [HD][T]
    unsigned short* pb = &Pb[w][0];
    const int key3 = l16 & 7;                  // K-read granule key
    const int key4 = key3 << 1;                // V/P granule key
    const int kg0  = (lk ^ key3) * 8;          // K granule offsets (shorts)
    const int kg1  = ((4 + lk) ^ key3) * 8;

    bf16x8 ones;
    {
        us8v o;
#pragma unroll
        for (int i = 0; i < 8; ++i) o[i] = 0x3F80;   // bf16 1.0
        ones = __builtin_bit_cast(bf16x8, o);
    }

    auto stage = [&](int buf, int kk0) {
#pragma unroll
        for (int i = 0; i < 4; ++i) {          // K: 1024 chunks
            int ch = (w * 4 + i) * 64 + lane;
            int r  = ch >> 3, cs = ch & 7, c = cs ^ (r & 7);
            gld_lds16(kpb + (size_t)(kk0 + r) * HDv + c * 8, &Ks[buf][ch * 8]);
        }
#pragma unroll
        for (int i = 0; i < 4; ++i) {          // V: 1024 chunks
            int ch = (w * 4 + i) * 64 + lane;
            int r  = ch >> 4, cs = ch & 15, c = cs ^ ((r & 7) << 1);
            gld_lds16(vpb + (size_t)r * Tv + kk0 + c * 8, &Vs[buf][ch * 8]);
        }
    };

    for (int ph = 0; ph < 2; ++ph) {
        const int tile = ph ? (31 - p) : p;
        const int qr0  = tile * 64 + w * 16;
        const int qg   = qr0 + l16;
        const int nkt  = (tile + 2) >> 1;      // 128-wide K tiles

        bf16x8 qf0, qf1;
        {
            const unsigned short* qp = q + head_off + (size_t)qg * HDv + lk * 8;
            qf0 = *(const bf16x8*)qp;
            qf1 = *(const bf16x8*)(qp + 32);
        }

        f32x4 acc[4] = {};
        f32x4 lacc = {};
        float m = -1e38f;

        int cur = 0;
        stage(0, 0);

        for (int j = 0; j < nkt; ++j) {
            const int kk0 = j * 128;
            if (j + 1 < nkt) { stage(cur ^ 1, kk0 + 128); VMCNT(8); }
            else             VMCNT(0);
            SBAR(); SCHED0();

            // S^T = K Q^T : s[ct][r] = S[k=kk0+ct*16+lk*4+r][q=l16]
            f32x4 s[8];
            __builtin_amdgcn_s_setprio(1);
#pragma unroll
            for (int ct = 0; ct < 8; ++ct) {
                const int rb = (ct * 16 + l16) * 64;
                bf16x8 k0 = *(const bf16x8*)&Ks[cur][rb + kg0];
                bf16x8 k1 = *(const bf16x8*)&Ks[cur][rb + kg1];
                f32x4 z = {};
                z = mfma_bf16(k0, qf0, z);
                z = mfma_bf16(k1, qf1, z);
                s[ct] = z;
            }
            __builtin_amdgcn_s_setprio(0);

            // causal mask (diagonal-overlapping tile only)
            if (kk0 + 127 > qr0) {
#pragma unroll
                for (int ct = 0; ct < 8; ++ct) {
                    const int kb2 = kk0 + ct * 16 + lk * 4;
#pragma unroll
                    for (int r = 0; r < 4; ++r)
                        if (kb2 + r > qg) s[ct][r] = -1e38f;
                }
            }

            // online softmax max (base-2 domain)
            f32x4 t0 = fmax4(fmax4(fmax4(s[0], s[1]), fmax4(s[2], s[3])),
                             fmax4(fmax4(s[4], s[5]), fmax4(s[6], s[7])));
            float pm = fmaxf(fmaxf(t0[0], t0[1]), fmaxf(t0[2], t0[3]));
            pm = fmaxf(pm, __shfl_xor(pm, 16));
            pm = fmaxf(pm, __shfl_xor(pm, 32));

            if (__all(pm - m <= 8.0f)) {       // defer-max (T13)
#pragma unroll
                for (int ct = 0; ct < 8; ++ct)
#pragma unroll
                    for (int r = 0; r < 4; ++r)
                        s[ct][r] = __builtin_exp2f(s[ct][r] - m);
            } else {
                const float mnew  = fmaxf(m, pm);
                const float alpha = __builtin_exp2f(m - mnew);
#pragma unroll
                for (int ct = 0; ct < 8; ++ct)
#pragma unroll
                    for (int r = 0; r < 4; ++r)
                        s[ct][r] = __builtin_exp2f(s[ct][r] - mnew);
#pragma unroll
                for (int nt = 0; nt < 4; ++nt)
                    acc[nt] *= alpha;
                lacc *= alpha;
                m = mnew;
            }

            // P^T -> LDS (granule-swizzled; k == short position within row)
#pragma unroll
            for (int ct = 0; ct < 8; ++ct) {
                uint2 wv;
                wv.x = cvt_pk_bf16(s[ct][0], s[ct][1]);
                wv.y = cvt_pk_bf16(s[ct][2], s[ct][3]);
                int gp = (((ct * 2 + (lk >> 1)) ^ key4) * 8) + (lk & 1) * 4;
                *(uint2*)&pb[l16 * 128 + gp] = wv;
            }

            // O^T += V^T P^T ; l via ones-MFMA (lane-local denominator)
            __builtin_amdgcn_s_setprio(1);
#pragma unroll
            for (int kh = 0; kh < 4; ++kh) {
                const int vg = ((kh * 4 + lk) ^ key4) * 8;
                bf16x8 pf = *(const bf16x8*)&pb[l16 * 128 + vg];
#pragma unroll
                for (int nt = 0; nt < 4; ++nt) {
                    bf16x8 vfr = *(const bf16x8*)&Vs[cur][(nt * 16 + l16) * 128 + vg];
                    acc[nt] = mfma_bf16(vfr, pf, acc[nt]);
                }
                lacc = mfma_bf16(ones, pf, lacc);
            }
            __builtin_amdgcn_s_setprio(0);

            LGKM0(); SBAR();
            cur ^= 1;
        }

        // epilogue: lane-local normalize, packed 8B stores
        const float rl = 1.0f / lacc[0];
        const size_t ybase = ((size_t)(b * Tv + qg)) * Cv + h * HDv + lk * 4;
#pragma unroll
        for (int nt = 0; nt < 4; ++nt) {
            uint2 wv;
            wv.x = cvt_pk_bf16(acc[nt][0] * rl, acc[nt][1] * rl);
            wv.y = cvt_pk_bf16(acc[nt][2] * rl, acc[nt][3] * rl);
            *(uint2*)&y[ybase + nt * 16] = wv;
        }
    }
}

extern "C" void kernel_launch(void* const* d_in, const int* in_sizes, int n_in,
                              void* d_out, int out_size, void* d_ws, size_t ws_size,
                              hipStream_t stream) {
    const float* x  = (const float*)d_in[0];
    const float* Wk = (const float*)d_in[1];
    const float* bk = (const float*)d_in[2];
    const float* Wq = (const float*)d_in[3];
    const float* bq = (const float*)d_in[4];
    const float* Wv = (const float*)d_in[5];
    const float* bv = (const float*)d_in[6];
    const float* Wp = (const float*)d_in[7];
    const float* bp = (const float*)d_in[8];

    // workspace layout (ushorts); total 40 MB
    unsigned short* ws   = (unsigned short*)d_ws;
    unsigned short* xb   = ws;                   // 4194304 (reused as yb)
    unsigned short* wqkb = xb   + 4194304;       // 2097152: Wq rows then Wk rows
    unsigned short* wvb  = wqkb + 2097152;       // 1048576
    unsigned short* wpb  = wvb  + 1048576;       // 1048576
    unsigned short* qb   = wpb  + 1048576;       // 4194304, head-split, pre-scaled
    unsigned short* kb   = qb   + 4194304;       // 4194304, head-split (qb+4194304!)
    unsigned short* vtb  = kb   + 4194304;       // 4194304, V^T [B*H][HD][T]
    unsigned short* yb   = xb;                   // reuse: x dead after QKV GEMMs
    (void)kb;

    cvt_kernel<<<4096, 256, 0, stream>>>(x, xb, 4194304);
    cvt4_kernel<<<4096, 256, 0, stream>>>(Wq, Wk, Wv, Wp,
                                          wqkb, wqkb + 1048576, wvb, wpb);

    // fused Q+K+V^T projections in one launch (1024 blocks, 4/CU)
    gemm_qkv<<<1024, 256, 0, stream>>>(xb, wqkb, wvb, bq, bk, bv, qb, vtb,
                                       0.125f * LOG2E);

    attn_kernel<<<512, 256, 0, stream>>>(qb, kb, vtb, yb);

    // output projection: 128x64, BK=64, grid (16,32)=512
    dim3 gp(Cv / 64, (Bv * Tv) / 128);
    gemm_64<<<gp, 256, 0, stream>>>(yb, wpb, bp, (float*)d_out, Cv, Cv);
}

// Round 11
// 127.914 us; speedup vs baseline: 1.4446x; 1.0002x over previous
//
#include <hip/hip_runtime.h>
#include <stdint.h>

// Problem constants
#define Bv  2
#define Tv  2048
#define Cv  1024
#define Hv  16
#define HDv 64
#define LOG2E 1.44269504088896340736f

typedef __bf16 bf16x8 __attribute__((ext_vector_type(8)));
typedef float f32x4 __attribute__((ext_vector_type(4)));
typedef unsigned short us4v __attribute__((ext_vector_type(4)));
typedef unsigned short us8v __attribute__((ext_vector_type(8)));

#define VMCNT(n) asm volatile("s_waitcnt vmcnt(" #n ")" ::: "memory")
#define LGKM0()  asm volatile("s_waitcnt lgkmcnt(0)" ::: "memory")
#define SBAR()   __builtin_amdgcn_s_barrier()
#define SCHED0() __builtin_amdgcn_sched_barrier(0)

static __device__ __forceinline__ unsigned short f2bf(float f) {
    unsigned int u = __builtin_bit_cast(unsigned int, f);
    u += 0x7FFFu + ((u >> 16) & 1u);   // round-to-nearest-even
    return (unsigned short)(u >> 16);
}

static __device__ __forceinline__ unsigned int cvt_pk_bf16(float lo, float hi) {
    unsigned int w;
    asm("v_cvt_pk_bf16_f32 %0, %1, %2" : "=v"(w) : "v"(lo), "v"(hi));
    return w;
}

static __device__ __forceinline__ void gld_lds16(const void* g, void* l) {
    __builtin_amdgcn_global_load_lds(
        (const __attribute__((address_space(1))) void*)g,
        (__attribute__((address_space(3))) void*)l, 16, 0, 0);
}

static __device__ __forceinline__ f32x4 mfma_bf16(bf16x8 a, bf16x8 b, f32x4 c) {
    return __builtin_amdgcn_mfma_f32_16x16x32_bf16(a, b, c, 0, 0, 0);
}

static __device__ __forceinline__ f32x4 fmax4(f32x4 a, f32x4 b) {
    f32x4 r;
    r[0] = fmaxf(a[0], b[0]); r[1] = fmaxf(a[1], b[1]);
    r[2] = fmaxf(a[2], b[2]); r[3] = fmaxf(a[3], b[3]);
    return r;
}

// ---------------- fp32 -> bf16 conversion ----------------
__global__ __launch_bounds__(256) void cvt_kernel(const float* __restrict__ in,
                                                  unsigned short* __restrict__ out,
                                                  int n) {
    int i = (blockIdx.x * 256 + threadIdx.x) * 4;
    if (i >= n) return;
    float4 v = *(const float4*)(in + i);
    us4v o;
    o[0] = f2bf(v.x); o[1] = f2bf(v.y); o[2] = f2bf(v.z); o[3] = f2bf(v.w);
    *(us4v*)(out + i) = o;
}

// 4 weight matrices (1M elements each) in one launch
__global__ __launch_bounds__(256) void cvt4_kernel(const float* __restrict__ a,
                                                   const float* __restrict__ b,
                                                   const float* __restrict__ c,
                                                   const float* __restrict__ d,
                                                   unsigned short* __restrict__ oa,
                                                   unsigned short* __restrict__ ob,
                                                   unsigned short* __restrict__ oc,
                                                   unsigned short* __restrict__ od) {
    const int sel = blockIdx.x >> 10;
    const float* in = sel == 0 ? a : sel == 1 ? b : sel == 2 ? c : d;
    unsigned short* out = sel == 0 ? oa : sel == 1 ? ob : sel == 2 ? oc : od;
    int i = ((blockIdx.x & 1023) * 256 + threadIdx.x) * 4;
    float4 v = *(const float4*)(in + i);
    us4v o;
    o[0] = f2bf(v.x); o[1] = f2bf(v.y); o[2] = f2bf(v.z); o[3] = f2bf(v.w);
    *(us4v*)(out + i) = o;
}

// ---------------- Fused QKV projection GEMM (1024 blocks) ----------------
// id < 512:  QK part, 128x128 tile, BK=32 dbuf, counted vmcnt. C = x @ [Wq;Wk]^T.
//            n<1024 -> q (scaled, bias bq) at qout; n>=1024 -> k (bias bk) at qout+4M.
// id >= 512: V^T part, 128(chan)x64(tok) tile, BK=32 dbuf. out vt[(tok>>11)*1024+ch][tok&2047].
// Co-resident groups {i,i+256,i+512,i+768} = 2 qk + 2 vt blocks -> balanced CU load.
__global__ __launch_bounds__(256) void gemm_qkv(const unsigned short* __restrict__ X,
                                                const unsigned short* __restrict__ Wqk,
                                                const unsigned short* __restrict__ Wv,
                                                const float* __restrict__ bq,
                                                const float* __restrict__ bk,
                                                const float* __restrict__ bv,
                                                unsigned short* __restrict__ qout,
                                                unsigned short* __restrict__ vtout,
                                                float scale) {
    __shared__ unsigned short As[2][128 * 32];
    __shared__ unsigned short Bs[2][128 * 32];
    const int K = Cv;

    const int tid  = threadIdx.x;
    const int lane = tid & 63;
    const int w    = tid >> 6;
    const int wr   = w >> 1, wc = w & 1;
    const int l16  = lane & 15;
    const int lk8  = (lane >> 4) * 8;
    const int id   = blockIdx.x;

    if (id < 512) {
        const int n0 = (id & 15) * 128;
        const int m0 = (id >> 4) * 128;
        f32x4 acc[4][4] = {};
        const int srow = tid >> 2;
        const int skc  = (tid & 3) * 8;

        auto stageAB = [&](int buf, int k0) {
            gld_lds16(X   + (size_t)(m0 + srow)      * K + k0 + skc, &As[buf][(size_t)tid * 8]);
            gld_lds16(X   + (size_t)(m0 + srow + 64) * K + k0 + skc, &As[buf][(size_t)(tid + 256) * 8]);
            gld_lds16(Wqk + (size_t)(n0 + srow)      * K + k0 + skc, &Bs[buf][(size_t)tid * 8]);
            gld_lds16(Wqk + (size_t)(n0 + srow + 64) * K + k0 + skc, &Bs[buf][(size_t)(tid + 256) * 8]);
        };

        int buf = 0;
        stageAB(0, 0);
        for (int k0 = 0; k0 < K; k0 += 32) {
            if (k0 + 32 < K) { stageAB(buf ^ 1, k0 + 32); VMCNT(4); }
            else             VMCNT(0);
            SBAR(); SCHED0();

            bf16x8 af[4], bf[4];
#pragma unroll
            for (int mf = 0; mf < 4; ++mf)
                af[mf] = *(const bf16x8*)&As[buf][(wr * 64 + mf * 16 + l16) * 32 + lk8];
#pragma unroll
            for (int nf = 0; nf < 4; ++nf)
                bf[nf] = *(const bf16x8*)&Bs[buf][(wc * 64 + nf * 16 + l16) * 32 + lk8];
#pragma unroll
            for (int mf = 0; mf < 4; ++mf)
#pragma unroll
                for (int nf = 0; nf < 4; ++nf)
                    acc[mf][nf] = mfma_bf16(af[mf], bf[nf], acc[mf][nf]);

            LGKM0(); SBAR();
            buf ^= 1;
        }

#pragma unroll
        for (int mf = 0; mf < 4; ++mf)
#pragma unroll
            for (int nf = 0; nf < 4; ++nf)
#pragma unroll
                for (int r = 0; r < 4; ++r) {
                    int m = m0 + wr * 64 + mf * 16 + (lane >> 4) * 4 + r;
                    int n = n0 + wc * 64 + nf * 16 + l16;
                    int sel = n >> 10, ch = n & 1023;
                    float bia = sel ? bk[ch] : bq[ch];
                    float v = (acc[mf][nf][r] + bia) * (sel ? 1.0f : scale);
                    int b = m >> 11, t = m & (Tv - 1);
                    int h = ch >> 6, d = ch & (HDv - 1);
                    qout[(size_t)sel * 4194304 +
                         (((size_t)(b * Hv + h)) * Tv + t) * HDv + d] = f2bf(v);
                }
    } else {
        const int vid = id - 512;
        const int n0 = (vid & 63) * 64;    // token tile
        const int m0 = (vid >> 6) * 128;   // channel tile
        f32x4 acc[4][2] = {};

        auto stageV = [&](int buf, int k0) {
#pragma unroll
            for (int i = 0; i < 2; ++i) {
                int ch = i * 256 + tid, r = ch >> 2, cc = (ch & 3) * 8;
                gld_lds16(Wv + (size_t)(m0 + r) * K + k0 + cc, &As[buf][(size_t)ch * 8]);
            }
            {
                int r = tid >> 2, cc = (tid & 3) * 8;
                gld_lds16(X + (size_t)(n0 + r) * K + k0 + cc, &Bs[buf][(size_t)tid * 8]);
            }
        };

        int buf = 0;
        stageV(0, 0);
        for (int k0 = 0; k0 < K; k0 += 32) {
            if (k0 + 32 < K) { stageV(buf ^ 1, k0 + 32); VMCNT(3); }
            else             VMCNT(0);
            SBAR(); SCHED0();

            bf16x8 af[4], bf[2];
#pragma unroll
            for (int mf = 0; mf < 4; ++mf)
                af[mf] = *(const bf16x8*)&As[buf][(wr * 64 + mf * 16 + l16) * 32 + lk8];
#pragma unroll
            for (int nf = 0; nf < 2; ++nf)
                bf[nf] = *(const bf16x8*)&Bs[buf][(wc * 32 + nf * 16 + l16) * 32 + lk8];
#pragma unroll
            for (int mf = 0; mf < 4; ++mf)
#pragma unroll
                for (int nf = 0; nf < 2; ++nf)
                    acc[mf][nf] = mfma_bf16(af[mf], bf[nf], acc[mf][nf]);

            LGKM0(); SBAR();
            buf ^= 1;
        }

#pragma unroll
        for (int mf = 0; mf < 4; ++mf)
#pragma unroll
            for (int nf = 0; nf < 2; ++nf)
#pragma unroll
                for (int r = 0; r < 4; ++r) {
                    int m = m0 + wr * 64 + mf * 16 + (lane >> 4) * 4 + r;  // channel
                    int n = n0 + wc * 32 + nf * 16 + l16;                  // token
                    float v = acc[mf][nf][r] + bv[m];
                    vtout[((size_t)(n >> 11) * 1024 + m) * Tv + (n & (Tv - 1))] = f2bf(v);
                }
    }
}

// ---------------- GEMM 128(M)x64(N), BK=64, XOR-swizzled LDS dbuf (P projection) ------
__global__ __launch_bounds__(256) void gemm_64(const unsigned short* __restrict__ A,
                                               const unsigned short* __restrict__ Bm,
                                               const float* __restrict__ bias0,
                                               float* __restrict__ out,
                                               int N, int K) {
    __shared__ unsigned short As[2][128 * 64];
    __shared__ unsigned short Bs[2][64 * 64];

    const int tid  = threadIdx.x;
    const int lane = tid & 63;
    const int w    = tid >> 6;
    const int wr   = w >> 1, wc = w & 1;
    const int m0   = blockIdx.y * 128;
    const int n0   = blockIdx.x * 64;
    const int l16  = lane & 15;
    const int lk   = (lane >> 4);

    f32x4 acc[4][2] = {};

    auto stageAB = [&](int buf, int k0) {
#pragma unroll
        for (int i = 0; i < 4; ++i) {
            int ch = i * 256 + tid, r = ch >> 3, cs = ch & 7, c = cs ^ (r & 7);
            gld_lds16(A + (size_t)(m0 + r) * K + k0 + c * 8, &As[buf][(size_t)ch * 8]);
        }
#pragma unroll
        for (int i = 0; i < 2; ++i) {
            int ch = i * 256 + tid, r = ch >> 3, cs = ch & 7, c = cs ^ (r & 7);
            gld_lds16(Bm + (size_t)(n0 + r) * K + k0 + c * 8, &Bs[buf][(size_t)ch * 8]);
        }
    };

    int buf = 0;
    stageAB(0, 0);
    for (int k0 = 0; k0 < K; k0 += 64) {
        if (k0 + 64 < K) { stageAB(buf ^ 1, k0 + 64); VMCNT(6); }
        else             VMCNT(0);
        SBAR(); SCHED0();

#pragma unroll
        for (int ks = 0; ks < 2; ++ks) {
            bf16x8 af[4], bf[2];
#pragma unroll
            for (int mf = 0; mf < 4; ++mf) {
                int row = wr * 64 + mf * 16 + l16;
                af[mf] = *(const bf16x8*)&As[buf][(row * 8 + ((ks * 4 + lk) ^ (row & 7))) * 8];
            }
#pragma unroll
            for (int nf = 0; nf < 2; ++nf) {
                int row = wc * 32 + nf * 16 + l16;
                bf[nf] = *(const bf16x8*)&Bs[buf][(row * 8 + ((ks * 4 + lk) ^ (row & 7))) * 8];
            }
#pragma unroll
            for (int mf = 0; mf < 4; ++mf)
#pragma unroll
                for (int nf = 0; nf < 2; ++nf)
                    acc[mf][nf] = mfma_bf16(af[mf], bf[nf], acc[mf][nf]);
        }

        LGKM0(); SBAR();
        buf ^= 1;
    }

#pragma unroll
    for (int mf = 0; mf < 4; ++mf)
#pragma unroll
        for (int nf = 0; nf < 2; ++nf)
#pragma unroll
            for (int r = 0; r < 4; ++r) {
                int m = m0 + wr * 64 + mf * 16 + (lane >> 4) * 4 + r;
                int n = n0 + wc * 32 + nf * 16 + l16;
                out[(size_t)m * N + n] = acc[mf][nf][r] + bias0[n];
            }
}

// ---------------- causal flash attention: KVBLK=128, sequential pair, MFMA-l ----------
// Block = 4 waves = 64 q-rows; phases (p, 31-p): ceil((p+1)/2)+ceil((32-p)/2) = 17 iters
// per block, CONSTANT -> perfectly balanced. K(128x64), V^T(64x128) staged to LDS
// (dbuf, counted vmcnt(8), source-side XOR pre-swizzle). l computed by ones-MFMA
// (lane-local in acc; rescales with alpha like O) -> no psum tree/shuffles.
// LDS: 32+32+16 = 80 KB -> exactly 2 blocks/CU.
__global__ __launch_bounds__(256) void attn_kernel(const unsigned short* __restrict__ q,
                                                   const unsigned short* __restrict__ k,
                                                   const unsigned short* __restrict__ vt,
                                                   unsigned short* __restrict__ y) {
    __shared__ __align__(16) unsigned short Ks[2][128 * 64];   // rows=k (128), 8 granules, key r&7
    __shared__ __align__(16) unsigned short Vs[2][64 * 128];   // rows=d (64), 16 granules, key (r&7)<<1
    __shared__ __align__(16) unsigned short Pb[4][16 * 128];   // rows=q (16), 16 granules, key (q&7)<<1

    const int tid  = threadIdx.x;
    const int lane = tid & 63;
    const int w    = tid >> 6;
    const int l16  = lane & 15;
    const int lk   = lane >> 4;

    const int lb   = blockIdx.x;               // 512 blocks
    const int xcd  = lb & 7;
    const int rest = lb >> 3;                  // 0..63
    const int bh   = xcd * 4 + (rest >> 4);
    const int p    = rest & 15;

    const int b = bh >> 4, h = bh & (Hv - 1);
    const size_t head_off = (size_t)bh * (Tv * HDv);
    const unsigned short* kpb = k  + head_off;
    const unsigned short* vpb = vt + head_off;     // [HD][T]
    unsigned short* pb = &Pb[w][0];
    const int key3 = l16 & 7;                  // K-read granule key
    const int key4 = key3 << 1;                // V/P granule key
    const int kg0  = (lk ^ key3) * 8;          // K granule offsets (shorts)
    const int kg1  = ((4 + lk) ^ key3) * 8;

    bf16x8 ones;
    {
        us8v o;
#pragma unroll
        for (int i = 0; i < 8; ++i) o[i] = 0x3F80;   // bf16 1.0
        ones = __builtin_bit_cast(bf16x8, o);
    }

    auto stage = [&](int buf, int kk0) {
#pragma unroll
        for (int i = 0; i < 4; ++i) {          // K: 1024 chunks
            int ch = (w * 4 + i) * 64 + lane;
            int r  = ch >> 3, cs = ch & 7, c = cs ^ (r & 7);
            gld_lds16(kpb + (size_t)(kk0 + r) * HDv + c * 8, &Ks[buf][ch * 8]);
        }
#pragma unroll
        for (int i = 0; i < 4; ++i) {          // V: 1024 chunks
            int ch = (w * 4 + i) * 64 + lane;
            int r  = ch >> 4, cs = ch & 15, c = cs ^ ((r & 7) << 1);
            gld_lds16(vpb + (size_t)r * Tv + kk0 + c * 8, &Vs[buf][ch * 8]);
        }
    };

    for (int ph = 0; ph < 2; ++ph) {
        const int tile = ph ? (31 - p) : p;
        const int qr0  = tile * 64 + w * 16;
        const int qg   = qr0 + l16;
        const int nkt  = (tile + 2) >> 1;      // 128-wide K tiles

        bf16x8 qf0, qf1;
        {
            const unsigned short* qp = q + head_off + (size_t)qg * HDv + lk * 8;
            qf0 = *(const bf16x8*)qp;
            qf1 = *(const bf16x8*)(qp + 32);
        }

        f32x4 acc[4] = {};
        f32x4 lacc = {};
        float m = -1e38f;

        int cur = 0;
        stage(0, 0);

        for (int j = 0; j < nkt; ++j) {
            const int kk0 = j * 128;
            if (j + 1 < nkt) { stage(cur ^ 1, kk0 + 128); VMCNT(8); }
            else             VMCNT(0);
            SBAR(); SCHED0();

            // S^T = K Q^T : s[ct][r] = S[k=kk0+ct*16+lk*4+r][q=l16]
            f32x4 s[8];
            __builtin_amdgcn_s_setprio(1);
#pragma unroll
            for (int ct = 0; ct < 8; ++ct) {
                const int rb = (ct * 16 + l16) * 64;
                bf16x8 k0 = *(const bf16x8*)&Ks[cur][rb + kg0];
                bf16x8 k1 = *(const bf16x8*)&Ks[cur][rb + kg1];
                f32x4 z = {};
                z = mfma_bf16(k0, qf0, z);
                z = mfma_bf16(k1, qf1, z);
                s[ct] = z;
            }
            __builtin_amdgcn_s_setprio(0);

            // causal mask (diagonal-overlapping tile only)
            if (kk0 + 127 > qr0) {
#pragma unroll
                for (int ct = 0; ct < 8; ++ct) {
                    const int kb2 = kk0 + ct * 16 + lk * 4;
#pragma unroll
                    for (int r = 0; r < 4; ++r)
                        if (kb2 + r > qg) s[ct][r] = -1e38f;
                }
            }

            // online softmax max (base-2 domain)
            f32x4 t0 = fmax4(fmax4(fmax4(s[0], s[1]), fmax4(s[2], s[3])),
                             fmax4(fmax4(s[4], s[5]), fmax4(s[6], s[7])));
            float pm = fmaxf(fmaxf(t0[0], t0[1]), fmaxf(t0[2], t0[3]));
            pm = fmaxf(pm, __shfl_xor(pm, 16));
            pm = fmaxf(pm, __shfl_xor(pm, 32));

            if (__all(pm - m <= 8.0f)) {       // defer-max (T13)
#pragma unroll
                for (int ct = 0; ct < 8; ++ct)
#pragma unroll
                    for (int r = 0; r < 4; ++r)
                        s[ct][r] = __builtin_exp2f(s[ct][r] - m);
            } else {
                const float mnew  = fmaxf(m, pm);
                const float alpha = __builtin_exp2f(m - mnew);
#pragma unroll
                for (int ct = 0; ct < 8; ++ct)
#pragma unroll
                    for (int r = 0; r < 4; ++r)
                        s[ct][r] = __builtin_exp2f(s[ct][r] - mnew);
#pragma unroll
                for (int nt = 0; nt < 4; ++nt)
                    acc[nt] *= alpha;
                lacc *= alpha;
                m = mnew;
            }

            // P^T -> LDS (granule-swizzled; k == short position within row)
#pragma unroll
            for (int ct = 0; ct < 8; ++ct) {
                uint2 wv;
                wv.x = cvt_pk_bf16(s[ct][0], s[ct][1]);
                wv.y = cvt_pk_bf16(s[ct][2], s[ct][3]);
                int gp = (((ct * 2 + (lk >> 1)) ^ key4) * 8) + (lk & 1) * 4;
                *(uint2*)&pb[l16 * 128 + gp] = wv;
            }

            // O^T += V^T P^T ; l via ones-MFMA (lane-local denominator)
            __builtin_amdgcn_s_setprio(1);
#pragma unroll
            for (int kh = 0; kh < 4; ++kh) {
                const int vg = ((kh * 4 + lk) ^ key4) * 8;
                bf16x8 pf = *(const bf16x8*)&pb[l16 * 128 + vg];
#pragma unroll
                for (int nt = 0; nt < 4; ++nt) {
                    bf16x8 vfr = *(const bf16x8*)&Vs[cur][(nt * 16 + l16) * 128 + vg];
                    acc[nt] = mfma_bf16(vfr, pf, acc[nt]);
                }
                lacc = mfma_bf16(ones, pf, lacc);
            }
            __builtin_amdgcn_s_setprio(0);

            LGKM0(); SBAR();
            cur ^= 1;
        }

        // epilogue: lane-local normalize, packed 8B stores
        const float rl = 1.0f / lacc[0];
        const size_t ybase = ((size_t)(b * Tv + qg)) * Cv + h * HDv + lk * 4;
#pragma unroll
        for (int nt = 0; nt < 4; ++nt) {
            uint2 wv;
            wv.x = cvt_pk_bf16(acc[nt][0] * rl, acc[nt][1] * rl);
            wv.y = cvt_pk_bf16(acc[nt][2] * rl, acc[nt][3] * rl);
            *(uint2*)&y[ybase + nt * 16] = wv;
        }
    }
}

extern "C" void kernel_launch(void* const* d_in, const int* in_sizes, int n_in,
                              void* d_out, int out_size, void* d_ws, size_t ws_size,
                              hipStream_t stream) {
    const float* x  = (const float*)d_in[0];
    const float* Wk = (const float*)d_in[1];
    const float* bk = (const float*)d_in[2];
    const float* Wq = (const float*)d_in[3];
    const float* bq = (const float*)d_in[4];
    const float* Wv = (const float*)d_in[5];
    const float* bv = (const float*)d_in[6];
    const float* Wp = (const float*)d_in[7];
    const float* bp = (const float*)d_in[8];

    // workspace layout (ushorts); total 40 MB
    unsigned short* ws   = (unsigned short*)d_ws;
    unsigned short* xb   = ws;                   // 4194304 (reused as yb)
    unsigned short* wqkb = xb   + 4194304;       // 2097152: Wq rows then Wk rows
    unsigned short* wvb  = wqkb + 2097152;       // 1048576
    unsigned short* wpb  = wvb  + 1048576;       // 1048576
    unsigned short* qb   = wpb  + 1048576;       // 4194304, head-split, pre-scaled
    unsigned short* kb   = qb   + 4194304;       // 4194304, head-split (qb+4194304!)
    unsigned short* vtb  = kb   + 4194304;       // 4194304, V^T [B*H][HD][T]
    unsigned short* yb   = xb;                   // reuse: x dead after QKV GEMMs
    (void)kb;

    cvt_kernel<<<4096, 256, 0, stream>>>(x, xb, 4194304);
    cvt4_kernel<<<4096, 256, 0, stream>>>(Wq, Wk, Wv, Wp,
                                          wqkb, wqkb + 1048576, wvb, wpb);

    // fused Q+K+V^T projections in one launch (1024 blocks, 4/CU)
    gemm_qkv<<<1024, 256, 0, stream>>>(xb, wqkb, wvb, bq, bk, bv, qb, vtb,
                                       0.125f * LOG2E);

    attn_kernel<<<512, 256, 0, stream>>>(qb, kb, vtb, yb);

    // output projection: 128x64, BK=64, grid (16,32)=512
    dim3 gp(Cv / 64, (Bv * Tv) / 128);
    gemm_64<<<gp, 256, 0, stream>>>(yb, wpb, bp, (float*)d_out, Cv, Cv);
}